// Round 8
// baseline (1515.918 us; speedup 1.0000x reference)
//
#include <hip/hip_runtime.h>
#include <hip/hip_bf16.h>
#include <stdint.h>

#define B_ 16
#define S_ 2048
#define D_ 1024
#define H_ 4096
#define E_ 4
#define C_ 1000

typedef __attribute__((ext_vector_type(8))) short short8;
typedef __attribute__((ext_vector_type(4))) float f32x4;

__device__ __forceinline__ unsigned short f2bf(float f){
  unsigned u = __float_as_uint(f);
  u += 0x7fffu + ((u>>16)&1u);
  return (unsigned short)(u>>16);
}

__device__ __forceinline__ void gload16(const void* g, void* l){
  __builtin_amdgcn_global_load_lds(
    (const __attribute__((address_space(1))) unsigned*)(uintptr_t)g,
    (__attribute__((address_space(3))) unsigned*)(uintptr_t)l, 16, 0, 0);
}

// ---------------- K0: W1 [E][D][H] fp32 -> W1T [E][H][D] bf16 ----------------
__global__ __launch_bounds__(256) void k0_transpose(const float* __restrict__ W1,
                                                    unsigned short* __restrict__ w1t){
  __shared__ float t[64][65];
  int tid = threadIdx.x;
  int h0 = blockIdx.x*64, d0 = blockIdx.y*64, e = blockIdx.z;
  const float* src = W1 + ((size_t)e*D_ + d0)*H_ + h0;
#pragma unroll
  for (int i=0;i<4;i++){
    int idx = i*256 + tid;
    int d = idx>>4, h4 = idx&15;
    float4 v = *(const float4*)&src[(size_t)d*H_ + h4*4];
    t[d][h4*4+0]=v.x; t[d][h4*4+1]=v.y; t[d][h4*4+2]=v.z; t[d][h4*4+3]=v.w;
  }
  __syncthreads();
  unsigned short* dst = w1t + ((size_t)e*H_ + h0)*D_ + d0;
#pragma unroll
  for (int i=0;i<4;i++){
    int idx = i*256 + tid;
    int h = idx>>4, d4 = idx&15;
    ushort4 o;
    o.x = f2bf(t[d4*4+0][h]); o.y = f2bf(t[d4*4+1][h]);
    o.z = f2bf(t[d4*4+2][h]); o.w = f2bf(t[d4*4+3][h]);
    *(ushort4*)&dst[(size_t)h*D_ + d4*4] = o;
  }
}

// ---------------- K1: gating GEMV (fp32) + x->bf16 cast; logits only ----------
__global__ __launch_bounds__(256) void k1_gate(const float* __restrict__ x,
    const float* __restrict__ Wg, unsigned short* __restrict__ xbf,
    float4* __restrict__ logits4){
  int tid = threadIdx.x, lane = tid&63, wid = tid>>6;
  const float4* wg4 = (const float4*)Wg;
  float4 wr[16];
#pragma unroll
  for (int k=0;k<4;k++)
#pragma unroll
    for (int c=0;c<4;c++) wr[k*4+c] = wg4[(lane + 64*k)*4 + c];
  for (int it=0; it<16; ++it){
    int t = it*2048 + blockIdx.x*4 + wid;
    const float4* xr = (const float4*)(x + (size_t)t*D_);
    ushort4* xo = (ushort4*)(xbf + (size_t)t*D_);
    float4 acc = make_float4(0.f,0.f,0.f,0.f);
#pragma unroll
    for (int k=0;k<4;k++){
      float4 xv = xr[lane + 64*k];
      float4 w;
      w = wr[k*4+0]; acc.x += xv.x*w.x; acc.y += xv.x*w.y; acc.z += xv.x*w.z; acc.w += xv.x*w.w;
      w = wr[k*4+1]; acc.x += xv.y*w.x; acc.y += xv.y*w.y; acc.z += xv.y*w.z; acc.w += xv.y*w.w;
      w = wr[k*4+2]; acc.x += xv.z*w.x; acc.y += xv.z*w.y; acc.z += xv.z*w.z; acc.w += xv.z*w.w;
      w = wr[k*4+3]; acc.x += xv.w*w.x; acc.y += xv.w*w.y; acc.z += xv.w*w.z; acc.w += xv.w*w.w;
      ushort4 o; o.x=f2bf(xv.x); o.y=f2bf(xv.y); o.z=f2bf(xv.z); o.w=f2bf(xv.w);
      xo[lane + 64*k] = o;
    }
#pragma unroll
    for (int mk=32; mk; mk>>=1){
      acc.x += __shfl_xor(acc.x, mk);
      acc.y += __shfl_xor(acc.y, mk);
      acc.z += __shfl_xor(acc.z, mk);
      acc.w += __shfl_xor(acc.w, mk);
    }
    if (lane==0) logits4[t] = acc;
  }
}

// ---------------- K1b: per-token softmax/argmax + routing stats ---------------
__global__ __launch_bounds__(256) void k1b_route(const float4* __restrict__ logits4,
    const float* __restrict__ bg, float* __restrict__ gate, int* __restrict__ eidx,
    float* __restrict__ probSum, unsigned* __restrict__ cntBE,
    float* __restrict__ gateSum){
  __shared__ float ps_l[4], gs_l[4];
  __shared__ unsigned cn_l[4];
  int tid = threadIdx.x, lane = tid&63;
  if (tid<4){ ps_l[tid]=0.f; gs_l[tid]=0.f; cn_l[tid]=0u; }
  __syncthreads();
  int t = blockIdx.x*256 + tid;
  int bb = t>>11;
  float4 l = logits4[t];
  float l0=l.x+bg[0], l1=l.y+bg[1], l2=l.z+bg[2], l3=l.w+bg[3];
  int idx=0; float mv=l0;
  if (l1>mv){mv=l1;idx=1;}
  if (l2>mv){mv=l2;idx=2;}
  if (l3>mv){mv=l3;idx=3;}
  float e0=__expf(l0-mv), e1=__expf(l1-mv), e2=__expf(l2-mv), e3=__expf(l3-mv);
  float inv = 1.0f/(e0+e1+e2+e3);
  float gv = inv;
  eidx[t]=idx; gate[t]=gv;
  float pr[4]={e0*inv, e1*inv, e2*inv, e3*inv};
#pragma unroll
  for (int e=0;e<4;e++){
    float pv = pr[e];
    float gm = (idx==e) ? gv : 0.f;
    unsigned long long mk2 = __ballot(idx==e);
#pragma unroll
    for (int mk=32; mk; mk>>=1){
      pv += __shfl_xor(pv, mk);
      gm += __shfl_xor(gm, mk);
    }
    if (lane==0){
      atomicAdd(&ps_l[e], pv); atomicAdd(&gs_l[e], gm);
      atomicAdd(&cn_l[e], (unsigned)__popcll(mk2));
    }
  }
  __syncthreads();
  if (tid<4){
    atomicAdd(&probSum[tid], ps_l[tid]);
    atomicAdd(&gateSum[tid*16+bb], gs_l[tid]);
    atomicAdd(&cntBE[tid*16+bb], cn_l[tid]);
  }
}

// ---------------- K2a: wave-parallel offsets + tile table + aux loss ----------
__global__ __launch_bounds__(64) void k2a_offsets(const unsigned* __restrict__ cntBE,
    const float* __restrict__ probSum, unsigned* __restrict__ groupOff,
    unsigned* __restrict__ cursor, int* __restrict__ expertOff,
    int* __restrict__ tileTab, float* __restrict__ out_aux){
  int g = threadIdx.x;
  unsigned c = cntBE[g];
  unsigned x = c;
#pragma unroll
  for (int sft=1; sft<64; sft<<=1){
    unsigned y = __shfl_up(x, sft);
    if (g >= sft) x += y;
  }
  unsigned excl = x - c;
  groupOff[g] = excl;
  cursor[g*32] = excl;
  unsigned total = __shfl(x, 63);
  if (g==63) groupOff[64] = x;
  if ((g&15)==0) expertOff[g>>4] = (int)excl;
  if (g==63) expertOff[4] = (int)total;
  unsigned eb0=__shfl(excl,0), eb1=__shfl(excl,16), eb2=__shfl(excl,32), eb3=__shfl(excl,48);
  unsigned eb4=total;
  unsigned nt0=(eb1-eb0+255)>>8, nt1=(eb2-eb1+255)>>8, nt2=(eb3-eb2+255)>>8, nt3=(eb4-eb3+255)>>8;
  unsigned t1=nt0, t2=nt0+nt1, t3=t2+nt2, t4=t3+nt3;
  for (unsigned t=g; t<t4; t+=64){
    int e; unsigned base, ts;
    if (t<t1){e=0;base=eb0;ts=t;}
    else if (t<t2){e=1;base=eb1;ts=t-t1;}
    else if (t<t3){e=2;base=eb2;ts=t-t2;}
    else {e=3;base=eb3;ts=t-t3;}
    tileTab[t] = (int)(((base+ts*256)<<3) | (e<<1) | 1);
  }
  if (g==0){
    float aux = (float)(eb1-eb0)*probSum[0] + (float)(eb2-eb1)*probSum[1]
              + (float)(eb3-eb2)*probSum[2] + (float)(eb4-eb3)*probSum[3];
    *out_aux = aux * 4.0f/(32768.0f*32768.0f);
  }
}

// ---------------- K2b: counting-sort scatter ----------------
__global__ __launch_bounds__(256) void k2b_scatter(const int* __restrict__ eidx,
   const float* __restrict__ gate, unsigned* __restrict__ cursor,
   int* __restrict__ perm, float* __restrict__ gateP){
  int t = blockIdx.x*256 + threadIdx.x;
  int e = eidx[t]; int bb = t>>11; int g = e*16+bb;
  unsigned pos = atomicAdd(&cursor[g*32], 1u);
  perm[pos] = (int)t;
  gateP[pos] = gate[t];
}

// ---------------- K3: grouped up-GEMM, 256x256, 4-phase dual-barrier pipeline --
// STAGE_H: stage half-tile CH (A chunks 2CH,2CH+1 + B chunks 2CH,2CH+1) of tile KT.
#define STAGE_H(BUF, KT, CH) do{                                                    \
  _Pragma("unroll") for (int q=(CH)*2; q<(CH)*2+2; q++){                            \
    gload16(srcA[q] + (KT)*64, (char*)As + (BUF)*32768 + (q*512+tid)*16);           \
    gload16(srcB[q] + (KT)*64, (char*)Bs + (BUF)*32768 + (q*512+tid)*16);           \
  }                                                                                 \
}while(0)

// PHASE: {ds_read subtile; STAGE; barrier; setprio 16xMFMA; WAIT; barrier}
#define PHASE(BUF, RH, KK, READB, STAGECODE, WAITCODE) do{                          \
  int koff = (((KK)*4+p)^sw)<<3;                                                    \
  _Pragma("unroll") for (int rf=0;rf<4;rf++)                                        \
    af[rf] = *(const short8*)&As[BUF][wr*128 + (RH)*64 + rf*16 + m][koff];          \
  if (READB){                                                                       \
    _Pragma("unroll") for (int cf=0;cf<4;cf++)                                      \
      bfr[cf] = *(const short8*)&Bs[BUF][wc*64 + cf*16 + m][koff];                  \
  }                                                                                 \
  STAGECODE;                                                                        \
  asm volatile("" ::: "memory");                                                    \
  __builtin_amdgcn_s_barrier();                                                     \
  asm volatile("" ::: "memory");                                                    \
  __builtin_amdgcn_s_setprio(1);                                                    \
  _Pragma("unroll") for (int rf=0;rf<4;rf++)                                        \
    _Pragma("unroll") for (int cf=0;cf<4;cf++)                                      \
      acc[(RH)*4+rf][cf] = __builtin_amdgcn_mfma_f32_16x16x32_bf16(af[rf], bfr[cf], acc[(RH)*4+rf][cf], 0,0,0); \
  __builtin_amdgcn_s_setprio(0);                                                    \
  WAITCODE;                                                                         \
  asm volatile("" ::: "memory");                                                    \
  __builtin_amdgcn_s_barrier();                                                     \
}while(0)

#define NOOPC do{}while(0)
#define VM0 asm volatile("s_waitcnt vmcnt(0)" ::: "memory")

__global__ __launch_bounds__(512, 2) void k3_moe(const unsigned short* __restrict__ xbf,
    const unsigned short* __restrict__ w1t, const float* __restrict__ b1,
    const float* __restrict__ gateP, const int* __restrict__ perm,
    const int* __restrict__ expertOff, const int* __restrict__ tileTab,
    float* __restrict__ z){
  __shared__ unsigned short As[2][256][64];   // 64 KB
  __shared__ unsigned short Bs[2][256][64];   // 64 KB
  int tid = threadIdx.x, lane = tid&63, wid = tid>>6;
  int wgid = blockIdx.x;
  int xcd = wgid&7, rest = wgid>>3;
  int tile_m = (rest>>3)*4 + (xcd>>1);
  int col = (xcd&1)*8 + (rest&7);
  int te = tileTab[tile_m];
  if (!(te&1)) return;
  int e = (te>>1)&3;
  int rowStart = te>>3;
  int rowEnd = expertOff[e+1];
  int col0 = col*256;
  int wr = wid>>2, wc = wid&3;
  int m = lane&15, p = lane>>4, sw = m&7;
  int rld = tid>>3, ci = tid&7;
  int soff = (ci ^ (rld&7))<<3;               // XOR swizzle on SOURCE
  const unsigned short* srcA[4];
  const unsigned short* srcB[4];
#pragma unroll
  for (int q=0;q<4;q++){
    int rowq = q*64 + rld;
    int ri = rowStart + rowq; if (ri >= rowEnd) ri = rowEnd-1;
    srcA[q] = xbf + (size_t)perm[ri]*D_ + soff;
    srcB[q] = w1t + ((size_t)(e*H_ + col0 + rowq))*D_ + soff;
  }
  f32x4 acc[8][4];
  f32x4 vz = {0.f,0.f,0.f,0.f};
#pragma unroll
  for (int a=0;a<8;a++)
#pragma unroll
    for (int c2=0;c2<4;c2++) acc[a][c2] = vz;
  short8 af[4], bfr[4];

  STAGE_H(0, 0, 0); STAGE_H(0, 0, 1);
  VM0;
  __builtin_amdgcn_s_barrier();
  asm volatile("" ::: "memory");
#pragma unroll 2
  for (int kt=0; kt<16; ++kt){
    int buf = kt&1;
    if (kt<15){
      PHASE(buf, 0, 0, 1, STAGE_H(buf^1, kt+1, 0), NOOPC);
      PHASE(buf, 1, 0, 0, STAGE_H(buf^1, kt+1, 1), NOOPC);
    } else {
      PHASE(buf, 0, 0, 1, NOOPC, NOOPC);
      PHASE(buf, 1, 0, 0, NOOPC, NOOPC);
    }
    PHASE(buf, 0, 1, 1, NOOPC, NOOPC);
    PHASE(buf, 1, 1, 0, NOOPC, VM0);   // tile-close: drain next tile's stages
  }
  // epilogue: per-row b-masked relu/gate reduction into z[e*16+b]
  float b1v[4];
#pragma unroll
  for (int cf=0;cf<4;cf++) b1v[cf] = b1[e*H_ + col0 + wc*64 + cf*16 + m];
  float gv[8][4]; int bP[8];
  int bmin=15, bmax=0;
#pragma unroll
  for (int rf=0;rf<8;rf++){
    bP[rf]=0;
#pragma unroll
    for (int j=0;j<4;j++){
      int row = rowStart + wr*128 + rf*16 + p*4 + j;
      int real = row < rowEnd;
      int rr = real ? row : rowEnd-1;
      float gvv = real ? gateP[rr] : 0.f;
      int bb = perm[rr]>>11;
      gv[rf][j] = gvv; bP[rf] |= bb<<(4*j);
      bmin = min(bmin, bb); bmax = max(bmax, bb);
    }
  }
  bmin = min(bmin, __shfl_xor(bmin,16)); bmin = min(bmin, __shfl_xor(bmin,32));
  bmax = max(bmax, __shfl_xor(bmax,16)); bmax = max(bmax, __shfl_xor(bmax,32));
  for (int bv=bmin; bv<=bmax; ++bv){
    float zacc[4] = {0.f,0.f,0.f,0.f};
#pragma unroll
    for (int rf=0;rf<8;rf++){
      float w0 = (((bP[rf]>>0 )&15)==bv) ? gv[rf][0] : 0.f;
      float w1 = (((bP[rf]>>4 )&15)==bv) ? gv[rf][1] : 0.f;
      float w2 = (((bP[rf]>>8 )&15)==bv) ? gv[rf][2] : 0.f;
      float w3 = (((bP[rf]>>12)&15)==bv) ? gv[rf][3] : 0.f;
#pragma unroll
      for (int cf=0;cf<4;cf++){
        f32x4 a = acc[rf][cf];
        zacc[cf] += w0*fmaxf(a[0]+b1v[cf],0.f) + w1*fmaxf(a[1]+b1v[cf],0.f)
                  + w2*fmaxf(a[2]+b1v[cf],0.f) + w3*fmaxf(a[3]+b1v[cf],0.f);
      }
    }
#pragma unroll
    for (int cf=0;cf<4;cf++){
      float v = zacc[cf];
      v += __shfl_xor(v, 16);
      v += __shfl_xor(v, 32);
      if (p==0) atomicAdd(&z[(size_t)(e*16+bv)*H_ + col0 + wc*64 + cf*16 + m], v);
    }
  }
}

// ---------------- K4a: partial[e,j0][bb][:] = z-chunk @ W2-chunk --------------
__global__ __launch_bounds__(256) void k4a_down(const float* __restrict__ z,
    const float* __restrict__ W2, float* __restrict__ partial){
  __shared__ float zs[16*256];
  int tid = threadIdx.x;
  int d0 = blockIdx.x*256, j0 = blockIdx.y*256, e = blockIdx.z;
  for (int idx=tid; idx<4096; idx+=256){
    int bb = idx>>8, j = idx&255;
    zs[idx] = z[((size_t)(e*16+bb))*H_ + j0 + j];
  }
  __syncthreads();
  float acc[16];
#pragma unroll
  for (int bb=0;bb<16;bb++) acc[bb]=0.f;
  const float* w2b = W2 + ((size_t)e*H_ + j0)*D_ + d0 + tid;
  for (int j4=0; j4<256; j4+=4){
    float w0 = w2b[(size_t)(j4+0)*D_];
    float w1v= w2b[(size_t)(j4+1)*D_];
    float w2v= w2b[(size_t)(j4+2)*D_];
    float w3v= w2b[(size_t)(j4+3)*D_];
#pragma unroll
    for (int bb=0;bb<16;bb++){
      float4 zv = *(const float4*)&zs[bb*256 + j4];
      acc[bb] += zv.x*w0 + zv.y*w1v + zv.z*w2v + zv.w*w3v;
    }
  }
  int cidx = e*16 + (j0>>8);
#pragma unroll
  for (int bb=0;bb<16;bb++)
    partial[((size_t)cidx*16 + bb)*1024 + d0 + tid] = acc[bb];
}

// ---------------- K4b: pooled reduce -> plf[16][1024] ----------------
__global__ __launch_bounds__(256) void k4b_pool(const float* __restrict__ partial,
    const float* __restrict__ gateSum, const float* __restrict__ b2,
    float* __restrict__ plfbuf){
  int tid = threadIdx.x, bb = blockIdx.x, dq = blockIdx.y;
  int d = dq*256 + tid;
  float s = 0.f;
  for (int c=0;c<64;c++) s += partial[((size_t)c*16 + bb)*1024 + d];
  s += gateSum[0*16+bb]*b2[0*D_+d] + gateSum[1*16+bb]*b2[1*D_+d]
     + gateSum[2*16+bb]*b2[2*D_+d] + gateSum[3*16+bb]*b2[3*D_+d];
  plfbuf[bb*1024 + d] = s * (1.0f/2048.0f);
}

// ---------------- K4d: head partials over (C-chunk x D-chunk) ----------------
__global__ __launch_bounds__(256) void k4d_head(const float* __restrict__ plfbuf,
    const float* __restrict__ Wh, float* __restrict__ hpart){
  __shared__ float pls[16][128];
  int tid = threadIdx.x, cc = blockIdx.x, dk = blockIdx.y;
  for (int i=tid; i<2048; i+=256){
    int bb = i>>7, dd = i&127;
    pls[bb][dd] = plfbuf[bb*1024 + dk*128 + dd];
  }
  __syncthreads();
  int c = cc*256 + tid;
  if (c < C_){
    float acc[16];
#pragma unroll
    for (int bb=0;bb<16;bb++) acc[bb]=0.f;
    for (int dd=0; dd<128; ++dd){
      float whv = Wh[(size_t)(dk*128+dd)*C_ + c];
#pragma unroll
      for (int bb=0;bb<16;bb++) acc[bb] += pls[bb][dd]*whv;
    }
#pragma unroll
    for (int bb=0;bb<16;bb++)
      hpart[((size_t)dk*16 + bb)*C_ + c] = acc[bb];
  }
}

// ---------------- K4e: reduce 8 D-chunks + bh -> out ----------------
__global__ __launch_bounds__(256) void k4e_out(const float* __restrict__ hpart,
    const float* __restrict__ bh, float* __restrict__ out){
  int tid = threadIdx.x, bb = blockIdx.x;
  if (tid < 250){
    float4 a = ((const float4*)bh)[tid];
#pragma unroll
    for (int dk=0;dk<8;dk++){
      float4 v = *(const float4*)&hpart[((size_t)dk*16 + bb)*C_ + tid*4];
      a.x+=v.x; a.y+=v.y; a.z+=v.z; a.w+=v.w;
    }
    ((float4*)(out + (size_t)bb*C_))[tid] = a;
  }
}

extern "C" void kernel_launch(void* const* d_in, const int* in_sizes, int n_in,
                              void* d_out, int out_size, void* d_ws, size_t ws_size,
                              hipStream_t stream){
  (void)in_sizes; (void)n_in; (void)out_size; (void)ws_size;
  const float* x  = (const float*)d_in[0];
  const float* Wg = (const float*)d_in[1];
  const float* bg = (const float*)d_in[2];
  const float* W1 = (const float*)d_in[3];
  const float* b1 = (const float*)d_in[4];
  const float* W2 = (const float*)d_in[5];
  const float* b2 = (const float*)d_in[6];
  const float* Wh = (const float*)d_in[7];
  const float* bh = (const float*)d_in[8];
  float* out = (float*)d_out;
  char* ws = (char*)d_ws;

  float*    probSum  = (float*)(ws + 0);
  unsigned* cntBE    = (unsigned*)(ws + 64);
  float*    gateSum  = (float*)(ws + 320);
  unsigned* groupOff = (unsigned*)(ws + 576);
  int*      expertOff= (int*)(ws + 840);
  int*      tileTab  = (int*)(ws + 864);
  unsigned* cursor   = (unsigned*)(ws + 2048);
  float*    z        = (float*)(ws + 16384);      // 1MB -> ends 1064960
  float*    plfbuf   = (float*)(ws + 1064960);    // 64KB (reuses logits region, dead by then)
  float4*   logits4  = (float4*)(ws + 1064960);   // 512KB -> 1589248
  unsigned short* xbf = (unsigned short*)(ws + 1593344);  // 64MB -> 68702208
  float*    partial  = (float*)(ws + 1593344);    // 4MB (overlaps xbf; xbf dead post-k3)
  float*    hpart    = (float*)(ws + 6291456);    // 512KB (overlaps xbf; dead post-k3)
  int*      perm     = (int*)(ws + 68702208);
  float*    gate     = (float*)(ws + 68833280);
  int*      eidx     = (int*)(ws + 68964352);
  float*    gateP    = (float*)(ws + 69095424);
  unsigned short* w1t = (unsigned short*)(ws + 69226496); // 32MB -> 102780928

  hipMemsetAsync(ws, 0, 1064960, stream);   // counters + tables + z
  k0_transpose<<<dim3(64,16,4), 256, 0, stream>>>(W1, w1t);
  k1_gate<<<512, 256, 0, stream>>>(x, Wg, xbf, logits4);
  k1b_route<<<128, 256, 0, stream>>>(logits4, bg, gate, eidx, probSum, cntBE, gateSum);
  k2a_offsets<<<1, 64, 0, stream>>>(cntBE, probSum, groupOff, cursor, expertOff, tileTab, out + 16000);
  k2b_scatter<<<128, 256, 0, stream>>>(eidx, gate, cursor, perm, gateP);
  k3_moe<<<2112, 512, 0, stream>>>(xbf, w1t, b1, gateP, perm, expertOff, tileTab, z);
  k4a_down<<<dim3(4,16,4), 256, 0, stream>>>(z, W2, partial);
  k4b_pool<<<dim3(16,4), 256, 0, stream>>>(partial, gateSum, b2, plfbuf);
  k4d_head<<<dim3(4,8), 256, 0, stream>>>(plfbuf, Wh, hpart);
  k4e_out<<<16, 256, 0, stream>>>(hpart, bh, out);
}